// Round 7
// baseline (194.784 us; speedup 1.0000x reference)
//
#include <hip/hip_runtime.h>
#include <math.h>

#define B_    4
#define S_    2048
#define IN_   256
#define H_    128
#define M_    128
#define NROWS (B_ * S_)     // 8192
#define RPB   16
#define TPB   256
#define XPAD  260

typedef float f4_t __attribute__((ext_vector_type(4)));

// ---------------- Kernel 1: projections + h,n outputs + k,v,i,f spill ----------------
// (byte-identical to R3's proj)
__global__ __launch_bounds__(TPB) void xlstm_proj(
    const float* __restrict__ x,
    const float* __restrict__ c0,
    const float* __restrict__ n0,
    const float* __restrict__ w_q, const float* __restrict__ b_q,
    const float* __restrict__ w_k, const float* __restrict__ b_k,
    const float* __restrict__ w_v, const float* __restrict__ b_v,
    const float* __restrict__ w_i, const float* __restrict__ b_i,
    const float* __restrict__ w_f, const float* __restrict__ b_f,
    const float* __restrict__ w_o, const float* __restrict__ b_o,
    float* __restrict__ out_h,
    float* __restrict__ out_n,
    float* __restrict__ kws,
    float* __restrict__ vws,
    float* __restrict__ ifws)
{
    __shared__ float xs[RPB][XPAD];
    __shared__ float qs[RPB][M_];
    __shared__ float ks[RPB][M_];
    __shared__ float vs[RPB][M_];
    __shared__ float os_[RPB][M_];
    __shared__ float c0qs[RPB][M_];
    __shared__ float itf[RPB][2];
    __shared__ float scal[RPB][2];

    const int t    = threadIdx.x;
    const int row0 = blockIdx.x * RPB;

    for (int p4 = t; p4 < RPB * IN_ / 4; p4 += TPB) {
        int p = p4 * 4;
        float4 v = *(const float4*)(x + (size_t)row0 * IN_ + p);
        int r = p >> 8, c = p & 255;
        *(float4*)&xs[r][c] = v;
    }
    __syncthreads();

    const int col   = t & 127;
    const int rbase = (t >> 7) * 8;

    {
        float accq[8], acck[8], accv[8], acco[8];
        #pragma unroll
        for (int r = 0; r < 8; ++r) { accq[r]=0.f; acck[r]=0.f; accv[r]=0.f; acco[r]=0.f; }

        #pragma unroll 2
        for (int k4 = 0; k4 < IN_; k4 += 4) {
            float4 xr[8];
            #pragma unroll
            for (int r = 0; r < 8; ++r) xr[r] = *(const float4*)&xs[rbase + r][k4];

            int wi = k4 * H_ + col;
            float4 wq, wk, wv, wo;
            wq.x = w_q[wi]; wq.y = w_q[wi + H_]; wq.z = w_q[wi + 2*H_]; wq.w = w_q[wi + 3*H_];
            wk.x = w_k[wi]; wk.y = w_k[wi + M_]; wk.z = w_k[wi + 2*M_]; wk.w = w_k[wi + 3*M_];
            wv.x = w_v[wi]; wv.y = w_v[wi + M_]; wv.z = w_v[wi + 2*M_]; wv.w = w_v[wi + 3*M_];
            wo.x = w_o[wi]; wo.y = w_o[wi + H_]; wo.z = w_o[wi + 2*H_]; wo.w = w_o[wi + 3*H_];

            #pragma unroll
            for (int r = 0; r < 8; ++r) {
                accq[r] = fmaf(xr[r].x, wq.x, fmaf(xr[r].y, wq.y, fmaf(xr[r].z, wq.z, fmaf(xr[r].w, wq.w, accq[r]))));
                acck[r] = fmaf(xr[r].x, wk.x, fmaf(xr[r].y, wk.y, fmaf(xr[r].z, wk.z, fmaf(xr[r].w, wk.w, acck[r]))));
                accv[r] = fmaf(xr[r].x, wv.x, fmaf(xr[r].y, wv.y, fmaf(xr[r].z, wv.z, fmaf(xr[r].w, wv.w, accv[r]))));
                acco[r] = fmaf(xr[r].x, wo.x, fmaf(xr[r].y, wo.y, fmaf(xr[r].z, wo.z, fmaf(xr[r].w, wo.w, acco[r]))));
            }
        }

        const float kscale = 0.08838834764831843f;   // 1/sqrt(128)
        #pragma unroll
        for (int r = 0; r < 8; ++r) {
            int row = rbase + r;
            qs[row][col]  = accq[r] + b_q[col];
            ks[row][col]  = (acck[r] + b_k[col]) * kscale;
            vs[row][col]  = accv[r] + b_v[col];
            float oo      = acco[r] + b_o[col];
            os_[row][col] = 1.f / (1.f + __expf(-oo));
        }
    }

    if (t < 32) {
        int r = t & 15;
        const float* w = (t < 16) ? w_i : w_f;
        float acc = 0.f;
        for (int k = 0; k < IN_; ++k) acc = fmaf(xs[r][k], w[k], acc);
        if (t < 16) itf[r][0] = __expf(acc + b_i[0]);
        else        itf[r][1] = 1.f / (1.f + __expf(-(acc + b_f[0])));
    }
    __syncthreads();

    // c0q[r][m] = sum_j c0[m][j] * q[r][j]
    {
        float acc2[8];
        #pragma unroll
        for (int r = 0; r < 8; ++r) acc2[r] = 0.f;
        const float* c0row = c0 + (size_t)col * M_;
        #pragma unroll 2
        for (int j4 = 0; j4 < M_; j4 += 4) {
            float4 w4 = *(const float4*)(c0row + j4);
            #pragma unroll
            for (int r = 0; r < 8; ++r) {
                float4 q4 = *(const float4*)&qs[rbase + r][j4];
                acc2[r] = fmaf(w4.x, q4.x, fmaf(w4.y, q4.y, fmaf(w4.z, q4.z, fmaf(w4.w, q4.w, acc2[r]))));
            }
        }
        #pragma unroll
        for (int r = 0; r < 8; ++r) c0qs[rbase + r][col] = acc2[r];
    }

    if (t < 32) {
        int r = t & 15;
        float acc = 0.f;
        if (t < 16) {
            for (int j = 0; j < M_; ++j) acc = fmaf(ks[r][j], qs[r][j], acc);
            scal[r][0] = acc;
        } else {
            for (int j = 0; j < M_; ++j) acc = fmaf(n0[j], qs[r][j], acc);
            scal[r][1] = acc;
        }
    }
    __syncthreads();

    #pragma unroll
    for (int r = 0; r < 8; ++r) {
        int row = rbase + r;
        size_t grow = (size_t)(row0 + row);
        float iv = itf[row][0], fv = itf[row][1];
        float kv = ks[row][col];
        out_n[grow * M_ + col] = fmaf(fv, n0[col], iv * kv);
        float nq    = fmaf(fv, scal[row][1], iv * scal[row][0]);
        float denom = fmaxf(fabsf(nq), 1.0f);
        float ht = fmaf(fv, c0qs[row][col], iv * vs[row][col] * scal[row][0]) / denom;
        out_h[grow * H_ + col] = os_[row][col] * ht;
        kws[grow * M_ + col] = kv;
        vws[grow * M_ + col] = vs[row][col];
    }
    if (t < 32) {
        int r = t & 15;
        size_t grow = (size_t)(row0 + r);
        if (t < 16) ifws[grow * 2 + 0] = itf[r][0];
        else        ifws[grow * 2 + 1] = itf[r][1];
    }
}

// ---------------- Kernel 2: c stream, 16 rows per block, nt stores ----------------
// (byte-identical to R3's cstream)
__global__ __launch_bounds__(TPB) void xlstm_cstream(
    const float* __restrict__ c0,
    const float* __restrict__ kws,
    const float* __restrict__ vws,
    const float* __restrict__ ifws,
    float* __restrict__ out_c)
{
    const int t    = threadIdx.x;
    const int row0 = blockIdx.x * RPB;

    __shared__ float vsh[RPB][M_];
    __shared__ float ksh[RPB][M_];
    __shared__ float2 ish[RPB];

    for (int p4 = t; p4 < RPB * M_ / 4; p4 += TPB) {
        int idx = p4 * 4;
        int r = idx >> 7, c = idx & 127;
        *(float4*)&vsh[r][c] = *(const float4*)(vws + (size_t)row0 * M_ + idx);
        *(float4*)&ksh[r][c] = *(const float4*)(kws + (size_t)row0 * M_ + idx);
    }
    if (t < RPB) ish[t] = *(const float2*)(ifws + (size_t)(row0 + t) * 2);
    __syncthreads();

    const float iv0 = ish[0].x;   (void)iv0;
    float* dummy = 0;             (void)dummy;

    const int base = t * 4;
    const int j    = base & 127;

    #pragma unroll 2
    for (int ch = 0; ch < 16; ++ch) {
        int p = (ch << 10) + base;
        int m = p >> 7;
        float4 c0v = *(const float4*)(c0 + p);
        #pragma unroll
        for (int r = 0; r < RPB; ++r) {
            float4 k4 = *(const float4*)&ksh[r][j];
            float  s  = ish[r].x * vsh[r][m];
            f4_t o4;
            o4.x = fmaf(ish[r].y, c0v.x, s * k4.x);
            o4.y = fmaf(ish[r].y, c0v.y, s * k4.y);
            o4.z = fmaf(ish[r].y, c0v.z, s * k4.z);
            o4.w = fmaf(ish[r].y, c0v.w, s * k4.w);
            __builtin_nontemporal_store(o4,
                (f4_t*)(out_c + (size_t)(row0 + r) * (M_ * M_) + p));
        }
    }
}

extern "C" void kernel_launch(void* const* d_in, const int* in_sizes, int n_in,
                              void* d_out, int out_size, void* d_ws, size_t ws_size,
                              hipStream_t stream) {
    const float* x   = (const float*)d_in[0];
    const float* c0  = (const float*)d_in[1];
    const float* n0  = (const float*)d_in[2];
    const float* w_q = (const float*)d_in[3];  const float* b_q = (const float*)d_in[4];
    const float* w_k = (const float*)d_in[5];  const float* b_k = (const float*)d_in[6];
    const float* w_v = (const float*)d_in[7];  const float* b_v = (const float*)d_in[8];
    const float* w_i = (const float*)d_in[9];  const float* b_i = (const float*)d_in[10];
    const float* w_f = (const float*)d_in[11]; const float* b_f = (const float*)d_in[12];
    const float* w_o = (const float*)d_in[13]; const float* b_o = (const float*)d_in[14];

    float* out   = (float*)d_out;
    float* out_h = out;
    float* out_c = out + (size_t)NROWS * H_;
    float* out_n = out_c + (size_t)NROWS * M_ * M_;

    float* kws  = (float*)d_ws;
    float* vws  = kws + (size_t)NROWS * M_;
    float* ifws = vws + (size_t)NROWS * M_;

    // DECOMPOSITION PROBE: proj launched TWICE (idempotent — rewrites identical
    // values). T_round7 - T_round3 = one proj duration. Stream unchanged.
    hipLaunchKernelGGL(xlstm_proj, dim3(NROWS / RPB), dim3(TPB), 0, stream,
                       x, c0, n0, w_q, b_q, w_k, b_k, w_v, b_v,
                       w_i, b_i, w_f, b_f, w_o, b_o,
                       out_h, out_n, kws, vws, ifws);
    hipLaunchKernelGGL(xlstm_proj, dim3(NROWS / RPB), dim3(TPB), 0, stream,
                       x, c0, n0, w_q, b_q, w_k, b_k, w_v, b_v,
                       w_i, b_i, w_f, b_f, w_o, b_o,
                       out_h, out_n, kws, vws, ifws);

    hipLaunchKernelGGL(xlstm_cstream, dim3(NROWS / RPB), dim3(TPB), 0, stream,
                       c0, kws, vws, ifws, out_c);
}

// Round 8
// 147.817 us; speedup vs baseline: 1.3177x; 1.3177x over previous
//
#include <hip/hip_runtime.h>
#include <math.h>

#define B_    4
#define S_    2048
#define IN_   256
#define H_    128
#define M_    128
#define NROWS (B_ * S_)     // 8192
#define RPB   16
#define TPB   256
#define XPAD  260

typedef float f4_t __attribute__((ext_vector_type(4)));

// ---------------- Kernel 1: projections + h,n + k,v,i,f spill ----------------
// R3 structure, minus c0qs LDS (registers instead -> 48.5 KB LDS, 3 blocks/CU),
// minus serial t<32 sections (wave-parallel shfl_xor reductions).
__global__ __launch_bounds__(TPB) void xlstm_proj(
    const float* __restrict__ x,
    const float* __restrict__ c0,
    const float* __restrict__ n0,
    const float* __restrict__ w_q, const float* __restrict__ b_q,
    const float* __restrict__ w_k, const float* __restrict__ b_k,
    const float* __restrict__ w_v, const float* __restrict__ b_v,
    const float* __restrict__ w_i, const float* __restrict__ b_i,
    const float* __restrict__ w_f, const float* __restrict__ b_f,
    const float* __restrict__ w_o, const float* __restrict__ b_o,
    float* __restrict__ out_h,
    float* __restrict__ out_n,
    float* __restrict__ kws,
    float* __restrict__ vws,
    float* __restrict__ ifws)
{
    __shared__ float xs[RPB][XPAD];     // 16.6 KB
    __shared__ float qs[RPB][M_];       // 8 KB x 4 = 32 KB
    __shared__ float ks[RPB][M_];
    __shared__ float vs[RPB][M_];
    __shared__ float os_[RPB][M_];
    __shared__ float itf[RPB][2];
    __shared__ float scal[RPB][2];

    const int t    = threadIdx.x;
    const int row0 = blockIdx.x * RPB;

    for (int p4 = t; p4 < RPB * IN_ / 4; p4 += TPB) {
        int p = p4 * 4;
        float4 v = *(const float4*)(x + (size_t)row0 * IN_ + p);
        int r = p >> 8, c = p & 255;
        *(float4*)&xs[r][c] = v;
    }
    __syncthreads();

    const int col   = t & 127;
    const int rbase = (t >> 7) * 8;

    {
        float accq[8], acck[8], accv[8], acco[8];
        #pragma unroll
        for (int r = 0; r < 8; ++r) { accq[r]=0.f; acck[r]=0.f; accv[r]=0.f; acco[r]=0.f; }

        #pragma unroll 2
        for (int k4 = 0; k4 < IN_; k4 += 4) {
            float4 xr[8];
            #pragma unroll
            for (int r = 0; r < 8; ++r) xr[r] = *(const float4*)&xs[rbase + r][k4];

            int wi = k4 * H_ + col;
            float4 wq, wk, wv, wo;
            wq.x = w_q[wi]; wq.y = w_q[wi + H_]; wq.z = w_q[wi + 2*H_]; wq.w = w_q[wi + 3*H_];
            wk.x = w_k[wi]; wk.y = w_k[wi + M_]; wk.z = w_k[wi + 2*M_]; wk.w = w_k[wi + 3*M_];
            wv.x = w_v[wi]; wv.y = w_v[wi + M_]; wv.z = w_v[wi + 2*M_]; wv.w = w_v[wi + 3*M_];
            wo.x = w_o[wi]; wo.y = w_o[wi + H_]; wo.z = w_o[wi + 2*H_]; wo.w = w_o[wi + 3*H_];

            #pragma unroll
            for (int r = 0; r < 8; ++r) {
                accq[r] = fmaf(xr[r].x, wq.x, fmaf(xr[r].y, wq.y, fmaf(xr[r].z, wq.z, fmaf(xr[r].w, wq.w, accq[r]))));
                acck[r] = fmaf(xr[r].x, wk.x, fmaf(xr[r].y, wk.y, fmaf(xr[r].z, wk.z, fmaf(xr[r].w, wk.w, acck[r]))));
                accv[r] = fmaf(xr[r].x, wv.x, fmaf(xr[r].y, wv.y, fmaf(xr[r].z, wv.z, fmaf(xr[r].w, wv.w, accv[r]))));
                acco[r] = fmaf(xr[r].x, wo.x, fmaf(xr[r].y, wo.y, fmaf(xr[r].z, wo.z, fmaf(xr[r].w, wo.w, acco[r]))));
            }
        }

        const float kscale = 0.08838834764831843f;   // 1/sqrt(128)
        #pragma unroll
        for (int r = 0; r < 8; ++r) {
            int row = rbase + r;
            qs[row][col]  = accq[r] + b_q[col];
            ks[row][col]  = (acck[r] + b_k[col]) * kscale;
            vs[row][col]  = accv[r] + b_v[col];
            float oo      = acco[r] + b_o[col];
            os_[row][col] = 1.f / (1.f + __expf(-oo));
        }
    }

    // ---- gates, wave-parallel (uses only xs; before the qs-sync) ----
    {
        const int gr = t >> 4, gseg = t & 15;
        const float* xrow = &xs[gr][gseg * 16];
        float pi = 0.f, pf = 0.f;
        #pragma unroll
        for (int u = 0; u < 4; ++u) {
            float4 xv  = *(const float4*)(xrow + u * 4);
            float4 wiv = *(const float4*)(w_i + gseg * 16 + u * 4);
            float4 wfv = *(const float4*)(w_f + gseg * 16 + u * 4);
            pi = fmaf(xv.x, wiv.x, fmaf(xv.y, wiv.y, fmaf(xv.z, wiv.z, fmaf(xv.w, wiv.w, pi))));
            pf = fmaf(xv.x, wfv.x, fmaf(xv.y, wfv.y, fmaf(xv.z, wfv.z, fmaf(xv.w, wfv.w, pf))));
        }
        #pragma unroll
        for (int m = 1; m < 16; m <<= 1) { pi += __shfl_xor(pi, m); pf += __shfl_xor(pf, m); }
        if (gseg == 0) {
            itf[gr][0] = __expf(pi + b_i[0]);
            itf[gr][1] = 1.f / (1.f + __expf(-(pf + b_f[0])));
        }
    }
    __syncthreads();

    // ---- c0q in registers: c0q[r] = sum_j c0[col][j] * q[rbase+r][j] ----
    float c0qr[8];
    {
        #pragma unroll
        for (int r = 0; r < 8; ++r) c0qr[r] = 0.f;
        const float* c0row = c0 + (size_t)col * M_;
        #pragma unroll 2
        for (int j4 = 0; j4 < M_; j4 += 4) {
            float4 w4 = *(const float4*)(c0row + j4);
            #pragma unroll
            for (int r = 0; r < 8; ++r) {
                float4 q4 = *(const float4*)&qs[rbase + r][j4];
                c0qr[r] = fmaf(w4.x, q4.x, fmaf(w4.y, q4.y, fmaf(w4.z, q4.z, fmaf(w4.w, q4.w, c0qr[r]))));
            }
        }
    }

    // ---- kq, n0q wave-parallel ----
    {
        const int gr = t >> 4, gseg = t & 15;
        const int j0 = gseg * 8;
        float pkq = 0.f, pnq = 0.f;
        #pragma unroll
        for (int u = 0; u < 2; ++u) {
            float4 kk = *(const float4*)&ks[gr][j0 + u * 4];
            float4 qq = *(const float4*)&qs[gr][j0 + u * 4];
            float4 nn = *(const float4*)(n0 + j0 + u * 4);
            pkq = fmaf(kk.x, qq.x, fmaf(kk.y, qq.y, fmaf(kk.z, qq.z, fmaf(kk.w, qq.w, pkq))));
            pnq = fmaf(nn.x, qq.x, fmaf(nn.y, qq.y, fmaf(nn.z, qq.z, fmaf(nn.w, qq.w, pnq))));
        }
        #pragma unroll
        for (int m = 1; m < 16; m <<= 1) { pkq += __shfl_xor(pkq, m); pnq += __shfl_xor(pnq, m); }
        if (gseg == 0) { scal[gr][0] = pkq; scal[gr][1] = pnq; }
    }
    __syncthreads();

    #pragma unroll
    for (int r = 0; r < 8; ++r) {
        int row = rbase + r;
        size_t grow = (size_t)(row0 + row);
        float iv = itf[row][0], fv = itf[row][1];
        float kv = ks[row][col];
        out_n[grow * M_ + col] = fmaf(fv, n0[col], iv * kv);
        float nq    = fmaf(fv, scal[row][1], iv * scal[row][0]);
        float denom = fmaxf(fabsf(nq), 1.0f);
        float ht = fmaf(fv, c0qr[r], iv * vs[row][col] * scal[row][0]) / denom;
        out_h[grow * H_ + col] = os_[row][col] * ht;
        kws[grow * M_ + col] = kv;
        vws[grow * M_ + col] = vs[row][col];
    }
    if (t < 32) {
        int r = t & 15;
        size_t grow = (size_t)(row0 + r);
        if (t < 16) ifws[grow * 2 + 0] = itf[r][0];
        else        ifws[grow * 2 + 1] = itf[r][1];
    }
}

// ---------------- Kernel 2: c stream, 16 rows per block, nt stores ----------------
// (byte-identical to R3's cstream)
__global__ __launch_bounds__(TPB) void xlstm_cstream(
    const float* __restrict__ c0,
    const float* __restrict__ kws,
    const float* __restrict__ vws,
    const float* __restrict__ ifws,
    float* __restrict__ out_c)
{
    const int t    = threadIdx.x;
    const int row0 = blockIdx.x * RPB;

    __shared__ float vsh[RPB][M_];
    __shared__ float ksh[RPB][M_];
    __shared__ float2 ish[RPB];

    for (int p4 = t; p4 < RPB * M_ / 4; p4 += TPB) {
        int idx = p4 * 4;
        int r = idx >> 7, c = idx & 127;
        *(float4*)&vsh[r][c] = *(const float4*)(vws + (size_t)row0 * M_ + idx);
        *(float4*)&ksh[r][c] = *(const float4*)(kws + (size_t)row0 * M_ + idx);
    }
    if (t < RPB) ish[t] = *(const float2*)(ifws + (size_t)(row0 + t) * 2);
    __syncthreads();

    const int base = t * 4;
    const int j    = base & 127;

    #pragma unroll 2
    for (int ch = 0; ch < 16; ++ch) {
        int p = (ch << 10) + base;
        int m = p >> 7;
        float4 c0v = *(const float4*)(c0 + p);
        #pragma unroll
        for (int r = 0; r < RPB; ++r) {
            float4 k4 = *(const float4*)&ksh[r][j];
            float  s  = ish[r].x * vsh[r][m];
            f4_t o4;
            o4.x = fmaf(ish[r].y, c0v.x, s * k4.x);
            o4.y = fmaf(ish[r].y, c0v.y, s * k4.y);
            o4.z = fmaf(ish[r].y, c0v.z, s * k4.z);
            o4.w = fmaf(ish[r].y, c0v.w, s * k4.w);
            __builtin_nontemporal_store(o4,
                (f4_t*)(out_c + (size_t)(row0 + r) * (M_ * M_) + p));
        }
    }
}

extern "C" void kernel_launch(void* const* d_in, const int* in_sizes, int n_in,
                              void* d_out, int out_size, void* d_ws, size_t ws_size,
                              hipStream_t stream) {
    const float* x   = (const float*)d_in[0];
    const float* c0  = (const float*)d_in[1];
    const float* n0  = (const float*)d_in[2];
    const float* w_q = (const float*)d_in[3];  const float* b_q = (const float*)d_in[4];
    const float* w_k = (const float*)d_in[5];  const float* b_k = (const float*)d_in[6];
    const float* w_v = (const float*)d_in[7];  const float* b_v = (const float*)d_in[8];
    const float* w_i = (const float*)d_in[9];  const float* b_i = (const float*)d_in[10];
    const float* w_f = (const float*)d_in[11]; const float* b_f = (const float*)d_in[12];
    const float* w_o = (const float*)d_in[13]; const float* b_o = (const float*)d_in[14];

    float* out   = (float*)d_out;
    float* out_h = out;
    float* out_c = out + (size_t)NROWS * H_;
    float* out_n = out_c + (size_t)NROWS * M_ * M_;

    float* kws  = (float*)d_ws;
    float* vws  = kws + (size_t)NROWS * M_;
    float* ifws = vws + (size_t)NROWS * M_;

    hipLaunchKernelGGL(xlstm_proj, dim3(NROWS / RPB), dim3(TPB), 0, stream,
                       x, c0, n0, w_q, b_q, w_k, b_k, w_v, b_v,
                       w_i, b_i, w_f, b_f, w_o, b_o,
                       out_h, out_n, kws, vws, ifws);

    hipLaunchKernelGGL(xlstm_cstream, dim3(NROWS / RPB), dim3(TPB), 0, stream,
                       c0, kws, vws, ifws, out_c);
}